// Round 9
// baseline (141.535 us; speedup 1.0000x reference)
//
#include <hip/hip_runtime.h>
#include <hip/hip_bf16.h>

#define B_ 128
#define S_ 513
#define H_ 256
#define SH_ (S_ * H_)

typedef __attribute__((ext_vector_type(8))) short short8;
typedef __attribute__((ext_vector_type(4))) float f32x4;

// Pack 8 fp32 -> 8 bf16 (RNE) via the HW packed converter.
static __device__ inline short8 pack8(float4 a, float4 b) {
    union { short8 s; __hip_bfloat162 h[4]; } u;
    u.h[0] = __float22bfloat162_rn(make_float2(a.x, a.y));
    u.h[1] = __float22bfloat162_rn(make_float2(a.z, a.w));
    u.h[2] = __float22bfloat162_rn(make_float2(b.x, b.y));
    u.h[3] = __float22bfloat162_rn(make_float2(b.z, b.w));
    return u.s;
}
static __device__ inline short8 pack8v(f32x4 a, f32x4 b) {
    union { short8 s; __hip_bfloat162 h[4]; } u;
    u.h[0] = __float22bfloat162_rn(make_float2(a[0], a[1]));
    u.h[1] = __float22bfloat162_rn(make_float2(a[2], a[3]));
    u.h[2] = __float22bfloat162_rn(make_float2(b[0], b[1]));
    u.h[3] = __float22bfloat162_rn(make_float2(b[2], b[3]));
    return u.s;
}

// Prep: W fp32 -> bf16 in fragment-major layout (m, kc, d, 8) so W fragment
// loads are coalesced (16 lanes -> 256 B run). Also bias sum (256 floats).
__global__ void prep_kernel(const float* __restrict__ W,
                            const float* __restrict__ bias,
                            unsigned short* __restrict__ Wbf,
                            float* __restrict__ bsum) {
    int t = blockIdx.x * 256 + threadIdx.x;
    if (t < 5 * 32 * 256) {                 // one thread per (m, d, kc)
        int m  = t >> 13;                   // t / 8192
        int r  = t & 8191;
        int d  = r >> 5;
        int kc = r & 31;                    // 8-elem k-chunk
        const float* src = W + (((size_t)m * 256 + d) * 256 + kc * 8);
        float4 v0 = *(const float4*)src;
        float4 v1 = *(const float4*)(src + 4);
        *(short8*)(Wbf + ((size_t)(m * 32 + kc) * 256 + d) * 8) = pack8(v0, v1);
    }
    if (t < H_) {
        float s = 0.f;
#pragma unroll
        for (int i = 0; i < 5; ++i) s += bias[i * H_ + t];
        bsum[t] = s;
    }
}

// PRODUCER/CONSUMER wave specialization.
// R0-R8 diagnostic: vmcnt retires IN ORDER, so any wave that issues both
// stage loads and compute loads has its prefetch force-drained by the
// compiler's implicit vmcnt before the first compute-load use -> per-wave
// pipelining is structurally impossible; every block's HBM-read stream was
// bursty (silent during the K-loop) -> flat ~2.5 TB/s read duty.
//
// Block = 320 threads: wave 4 = pure producer (FIFO contains ONLY
// global_load_lds -> counted vmcnt(16) waits are exact, never drained);
// waves 0-3 = consumers (W frags from L2, LDS reads, MFMA, stores; no
// gload_lds). Ring of 3 x 16KB LDS slots (48 KB -> 3 blocks/CU),
// lookahead 2: producer always has >=1 stage (16 KB) in flight ->
// continuous HBM reads. ONE uniform raw s_barrier per tile (no
// __syncthreads vmcnt-drain). 4 tiles x 16 rows per block.
//
// Work map (b-major, R5/R7): bid>=6: mb=bid-6, b=mb>>3, par, q(0..3):
// rows r=0..63 -> s = (par?3:4)+q*128+2r (W3/W4 by parity). bid<6: edge,
// s=bid>>1 in {0,1,2}, 64 b-rows each (W0-2).
template <int MODE>
__global__ __launch_bounds__(320, 3)
void sel_gemm_kernel(const float* __restrict__ x,
                     const void* __restrict__ Wp,
                     const void* __restrict__ bp,
                     float* __restrict__ out) {
    __shared__ float As[3][16 * 256];       // 48 KB ring

    const int bid  = blockIdx.x;
    const int t    = threadIdx.x;
    const int lane = t & 63;
    const int w8   = t >> 6;        // 0..4 (4 = producer)
    const int lrow = lane & 15;
    const int quad = lane >> 4;

    int m_idx, rmaxg;
    size_t xrow0, rstride;
    if (bid < 6) {
        const int s  = bid >> 1;    // 0..2
        const int bh = bid & 1;
        m_idx   = s;
        xrow0   = (size_t)(bh * 64) * S_ + s;   // row r -> b = bh*64+r
        rstride = S_;
        rmaxg   = 63;
    } else {
        const int mb = bid - 6;     // 0..1023
        const int b   = mb >> 3;
        const int sub = mb & 7;
        const int par = sub & 1;
        const int q   = sub >> 1;   // 0..3
        m_idx   = par ? 3 : 4;
        xrow0   = (size_t)b * S_ + (par ? 3 : 4) + q * 128;  // r -> s=+2r
        rstride = 2;
        rmaxg   = 254 - q * 64;
        if (rmaxg > 63) rmaxg = 63;
    }

    const bool producer = (w8 == 4);

    // ---- Producer prologue: stage tiles 0 and 1 (16 gload_lds each; one
    // instruction = one full 1 KB row, wave-uniform LDS base + lane*16).
    // Per-lane GLOBAL chunk = lane^(it&7) so LDS chunk c holds global chunk
    // c^(it&7); consumer reads apply the same XOR (2-way bank alias, free).
    if (producer) {
#pragma unroll
        for (int tt = 0; tt < 2; ++tt) {
#pragma unroll
            for (int it = 0; it < 16; ++it) {
                int rg = tt * 16 + it;
                if (rg > rmaxg) rg = rmaxg;
                const float* src = x + (xrow0 + rstride * rg) * H_
                                     + ((lane ^ (it & 7)) << 2);
                __builtin_amdgcn_global_load_lds(
                    (const __attribute__((address_space(1))) unsigned int*)src,
                    (__attribute__((address_space(3))) unsigned int*)
                        &As[tt][it * 256],
                    16, 0, 0);
            }
        }
    }

    // ---- Consumer setup: bias along this wave's d-slice (ds = w8).
    f32x4 bj4[4];
    if (!producer) {
        if (MODE == 0) {
            const float* bsum = (const float*)bp;
#pragma unroll
            for (int j = 0; j < 4; ++j)
                bj4[j] = *(const f32x4*)(bsum + w8 * 64 + j * 16 + quad * 4);
        } else {
            const float* bias = (const float*)bp;
#pragma unroll
            for (int j = 0; j < 4; ++j) {
                const int d0 = w8 * 64 + j * 16 + quad * 4;
#pragma unroll
                for (int r = 0; r < 4; ++r) {
                    float sum = 0.f;
#pragma unroll
                    for (int i = 0; i < 5; ++i) sum += bias[i * H_ + d0 + r];
                    bj4[j][r] = sum;
                }
            }
        }
    }

    // ---- Main loop: one uniform barrier per tile.
#pragma unroll
    for (int tt = 0; tt < 4; ++tt) {
        if (producer) {
            // Stage tt complete? (stage tt+1 may stay in flight: FIFO holds
            // only stages, 16 per tile -> counted wait, no drain.)
            if (tt < 3) asm volatile("s_waitcnt vmcnt(16)" ::: "memory");
            else        asm volatile("s_waitcnt vmcnt(0)"  ::: "memory");
        }
        __builtin_amdgcn_s_barrier();       // tile tt ready; slot (tt+2)%3
        __builtin_amdgcn_sched_barrier(0);  // free (consumers done tt-1)

        if (producer) {
            if (tt + 2 < 4) {
                const int slot = (tt + 2) % 3;
#pragma unroll
                for (int it = 0; it < 16; ++it) {
                    int rg = (tt + 2) * 16 + it;
                    if (rg > rmaxg) rg = rmaxg;
                    const float* src = x + (xrow0 + rstride * rg) * H_
                                         + ((lane ^ (it & 7)) << 2);
                    __builtin_amdgcn_global_load_lds(
                        (const __attribute__((address_space(1))) unsigned int*)src,
                        (__attribute__((address_space(3))) unsigned int*)
                            &As[slot][it * 256],
                        16, 0, 0);
                }
            }
        } else {
            const float* Ab = As[tt % 3];
            f32x4 acc[4];
#pragma unroll
            for (int j = 0; j < 4; ++j) {
                f32x4 z = {0.f, 0.f, 0.f, 0.f};
                acc[j] = z;
            }

            // K-loop: 8 steps of 32. W frags from L2 (640 KB, hot);
            // x frag (16 rows) from LDS, XOR-deswizzled, cvt_pk'd to bf16.
#pragma unroll
            for (int kk = 0; kk < 8; ++kk) {
                short8 wfr[4];
                if (MODE == 0) {
                    const unsigned short* Wk =
                        (const unsigned short*)Wp +
                        ((size_t)(m_idx * 32 + kk * 4 + quad) * 256) * 8;
#pragma unroll
                    for (int j = 0; j < 4; ++j)
                        wfr[j] = *(const short8*)(Wk +
                                  (size_t)(w8 * 64 + j * 16 + lrow) * 8);
                } else {
                    const float* Wb = (const float*)Wp + (size_t)m_idx * H_ * H_;
#pragma unroll
                    for (int j = 0; j < 4; ++j) {
                        const float* wrow = Wb +
                            (size_t)(w8 * 64 + j * 16 + lrow) * H_
                            + kk * 32 + quad * 8;
                        float4 v0 = *(const float4*)wrow;
                        float4 v1 = *(const float4*)(wrow + 4);
                        wfr[j] = pack8(v0, v1);
                    }
                }

                const int g0 = kk * 8 + quad * 2;   // global 16B-chunk idx
                const int r  = lrow;                 // slot row 0..15
                f32x4 f0 = *(const f32x4*)&Ab[r * 256 + (((g0    ) ^ (r & 7)) << 2)];
                f32x4 f1 = *(const f32x4*)&Ab[r * 256 + (((g0 + 1) ^ (r & 7)) << 2)];
                short8 xf = pack8v(f0, f1);

#pragma unroll
                for (int j = 0; j < 4; ++j)
                    acc[j] = __builtin_amdgcn_mfma_f32_16x16x32_bf16(
                        wfr[j], xf, acc[j], 0, 0, 0);
            }

            // Epilogue: col(lane&15)=slot row, row(quad*4+reg)=d.
            const int rg = tt * 16 + lrow;
            if (rg <= rmaxg) {
#pragma unroll
                for (int j = 0; j < 4; ++j) {
                    const int d0 = w8 * 64 + j * 16 + quad * 4;
                    f32x4 v = acc[j] + bj4[j];
                    *(f32x4*)(out + (xrow0 + rstride * rg) * H_ + d0) = v;
                }
            }
        }
    }
}

extern "C" void kernel_launch(void* const* d_in, const int* in_sizes, int n_in,
                              void* d_out, int out_size, void* d_ws, size_t ws_size,
                              hipStream_t stream) {
    const float* x    = (const float*)d_in[0];
    const float* W    = (const float*)d_in[1];
    const float* bias = (const float*)d_in[2];
    float* out = (float*)d_out;

    const size_t w_elems  = (size_t)5 * H_ * H_;
    const size_t ws_need  = w_elems * sizeof(unsigned short) + H_ * sizeof(float);

    const int grid = 6 + 1024;
    if (ws_size >= ws_need) {
        unsigned short* Wbf = (unsigned short*)d_ws;
        float* bsum = (float*)((char*)d_ws + w_elems * sizeof(unsigned short));
        prep_kernel<<<dim3(160), dim3(256), 0, stream>>>(W, bias, Wbf, bsum);
        sel_gemm_kernel<0><<<dim3(grid), dim3(320), 0, stream>>>(
            x, (const void*)Wbf, (const void*)bsum, out);
    } else {
        sel_gemm_kernel<1><<<dim3(grid), dim3(320), 0, stream>>>(
            x, (const void*)W, (const void*)bias, out);
    }
}

// Round 10
// 131.121 us; speedup vs baseline: 1.0794x; 1.0794x over previous
//
#include <hip/hip_runtime.h>
#include <hip/hip_bf16.h>

#define B_ 128
#define S_ 513
#define H_ 256
#define SH_ (S_ * H_)

typedef __attribute__((ext_vector_type(8))) short short8;
typedef __attribute__((ext_vector_type(4))) float f32x4;

// Pack 8 fp32 -> 8 bf16 (RNE) via the HW packed converter.
static __device__ inline short8 pack8(float4 a, float4 b) {
    union { short8 s; __hip_bfloat162 h[4]; } u;
    u.h[0] = __float22bfloat162_rn(make_float2(a.x, a.y));
    u.h[1] = __float22bfloat162_rn(make_float2(a.z, a.w));
    u.h[2] = __float22bfloat162_rn(make_float2(b.x, b.y));
    u.h[3] = __float22bfloat162_rn(make_float2(b.z, b.w));
    return u.s;
}
static __device__ inline short8 pack8v(f32x4 a, f32x4 b) {
    union { short8 s; __hip_bfloat162 h[4]; } u;
    u.h[0] = __float22bfloat162_rn(make_float2(a[0], a[1]));
    u.h[1] = __float22bfloat162_rn(make_float2(a[2], a[3]));
    u.h[2] = __float22bfloat162_rn(make_float2(b[0], b[1]));
    u.h[3] = __float22bfloat162_rn(make_float2(b[2], b[3]));
    return u.s;
}

// Prep: W fp32 -> bf16 in fragment-major layout (m, kc, d, 8) so W fragment
// loads are coalesced (16 lanes -> 256 B run). Also bias sum (256 floats).
__global__ void prep_kernel(const float* __restrict__ W,
                            const float* __restrict__ bias,
                            unsigned short* __restrict__ Wbf,
                            float* __restrict__ bsum) {
    int t = blockIdx.x * 256 + threadIdx.x;
    if (t < 5 * 32 * 256) {                 // one thread per (m, d, kc)
        int m  = t >> 13;                   // t / 8192
        int r  = t & 8191;
        int d  = r >> 5;
        int kc = r & 31;                    // 8-elem k-chunk
        const float* src = W + (((size_t)m * 256 + d) * 256 + kc * 8);
        float4 v0 = *(const float4*)src;
        float4 v1 = *(const float4*)(src + 4);
        *(short8*)(Wbf + ((size_t)(m * 32 + kc) * 256 + d) * 8) = pack8(v0, v1);
    }
    if (t < H_) {
        float s = 0.f;
#pragma unroll
        for (int i = 0; i < 5; ++i) s += bias[i * H_ + t];
        bsum[t] = s;
    }
}

// R0-R9 synthesis: the only structures that work are coarse INDEPENDENT
// blocks with one barrier (R1/R7, 43-45 us); the flat ~2.5 TB/s equals the
// read DUTY CYCLE (reads silent during the K-loop's ~8 serial W L2-latency
// chains; copy ubench proves 6.3 TB/s at the same 50/50 R/W mix).
//
// This version = R7's skeleton with the compute phase made SHORT and
// CHAIN-FREE: 512 thr / 8 waves, each wave owns a 32-wide d-slice, so its
// whole W slice is 16 x b128 = 64 VGPR -- hoisted to registers BEFORE the
// barrier. W loads issue first, gload_lds stage second; the in-order vmcnt
// FIFO means __syncthreads' vmcnt(0) covers both, and W's L2 latency hides
// under the HBM stage. K-loop: pure LDS+MFMA, ZERO global ops (~1500 cyc vs
// ~4000 with chains) -> per-block read-silence shrinks ~2.5x; 2 blocks/CU
// (launch_bounds(512,4), ~115 VGPR) alternate to keep reads continuous.
//
// Work map (b-major, R5): bid<2048: b=bid>>4, par=sub&1, q=sub>>1 (0..7):
// 32 s-rows, s = (par?3:4)+q*64+2r (W3/W4). bid>=2048: 12 edge blocks,
// s=e>>2 in {0,1,2}, 32 b-rows each (W0-2).
template <int MODE>
__global__ __launch_bounds__(512, 4)
void sel_gemm_kernel(const float* __restrict__ x,
                     const void* __restrict__ Wp,
                     const void* __restrict__ bp,
                     float* __restrict__ out) {
    __shared__ float As[32 * 256];          // 32 KB, gload_lds (linear dest)

    const int bid  = blockIdx.x;
    const int t    = threadIdx.x;
    const int lane = t & 63;
    const int w8   = t >> 6;        // 0..7 : d-slice (w8*32)
    const int lrow = lane & 15;
    const int quad = lane >> 4;

    int m_idx, rmax;
    size_t xrow0, rstride;
    if (bid < 2048) {
        const int b   = bid >> 4;
        const int sub = bid & 15;
        const int par = sub & 1;
        const int q   = sub >> 1;           // 0..7
        const int sbase = (par ? 3 : 4) + q * 64;
        m_idx   = par ? 3 : 4;
        xrow0   = (size_t)b * S_ + sbase;   // row r -> s = sbase + 2r
        rstride = 2;
        rmax    = (512 - sbase) >> 1;
        if (rmax > 31) rmax = 31;
    } else {
        const int e  = bid - 2048;          // 0..11
        const int s  = e >> 2;              // 0..2
        const int bq = e & 3;
        m_idx   = s;
        xrow0   = (size_t)(bq * 32) * S_ + s;   // row r -> b = bq*32+r
        rstride = S_;
        rmax    = 31;
    }

    // ---- 1) W-hoist: this wave's 32-d slice, all K=256 -> 16 short8
    // (64 VGPR). Issued FIRST so its L2 latency hides under the HBM stage.
    short8 wfr[2][8];
    if (MODE == 0) {
        const unsigned short* Wb = (const unsigned short*)Wp;
#pragma unroll
        for (int kk = 0; kk < 8; ++kk) {
            const unsigned short* Wk =
                Wb + ((size_t)(m_idx * 32 + kk * 4 + quad) * 256) * 8;
#pragma unroll
            for (int j = 0; j < 2; ++j)
                wfr[j][kk] = *(const short8*)(Wk +
                              (size_t)(w8 * 32 + j * 16 + lrow) * 8);
        }
    } else {
        const float* Wb = (const float*)Wp + (size_t)m_idx * H_ * H_;
#pragma unroll
        for (int kk = 0; kk < 8; ++kk)
#pragma unroll
            for (int j = 0; j < 2; ++j) {
                const float* wrow = Wb +
                    (size_t)(w8 * 32 + j * 16 + lrow) * H_ + kk * 32 + quad * 8;
                float4 v0 = *(const float4*)wrow;
                float4 v1 = *(const float4*)(wrow + 4);
                wfr[j][kk] = pack8(v0, v1);
            }
    }

    // ---- 2) Stage x: 32 rows x 256 fp32 via gload_lds, 4 rows/wave (one
    // instruction = one full 1 KB row, wave-uniform LDS base + lane*16).
    // Per-lane GLOBAL chunk = lane^(row&7) so LDS chunk c holds global
    // chunk c^(row&7); K-loop reads apply the same XOR (<=2-way, free).
#pragma unroll
    for (int it = 0; it < 4; ++it) {
        const int row = w8 * 4 + it;        // 0..31
        int rg = row <= rmax ? row : rmax;  // clamp data; slot stays row
        const float* src = x + (xrow0 + rstride * rg) * H_
                             + ((lane ^ (row & 7)) << 2);
        __builtin_amdgcn_global_load_lds(
            (const __attribute__((address_space(1))) unsigned int*)src,
            (__attribute__((address_space(3))) unsigned int*)&As[row * 256],
            16, 0, 0);
    }

    // ---- Bias along this wave's d-slice.
    f32x4 bj[2];
    if (MODE == 0) {
        const float* bsum = (const float*)bp;
#pragma unroll
        for (int j = 0; j < 2; ++j)
            bj[j] = *(const f32x4*)(bsum + w8 * 32 + j * 16 + quad * 4);
    } else {
        const float* bias = (const float*)bp;
#pragma unroll
        for (int j = 0; j < 2; ++j) {
            const int d0 = w8 * 32 + j * 16 + quad * 4;
#pragma unroll
            for (int r = 0; r < 4; ++r) {
                float sum = 0.f;
#pragma unroll
                for (int i = 0; i < 5; ++i) sum += bias[i * H_ + d0 + r];
                bj[j][r] = sum;
            }
        }
    }

    f32x4 acc[2][2];
#pragma unroll
    for (int i = 0; i < 2; ++i)
#pragma unroll
        for (int j = 0; j < 2; ++j) {
            f32x4 z = {0.f, 0.f, 0.f, 0.f};
            acc[i][j] = z;
        }

    __syncthreads();   // vmcnt(0) drain: stage AND W-hoist complete

    // ---- 3) K-loop: 8 steps of 32. PURE LDS + register MFMA -- no global
    // memory operations of any kind inside the loop.
#pragma unroll
    for (int kk = 0; kk < 8; ++kk) {
        short8 xfr[2];
        const int g0 = kk * 8 + quad * 2;   // global 16B-chunk index
#pragma unroll
        for (int i = 0; i < 2; ++i) {
            const int r = i * 16 + lrow;
            f32x4 f0 = *(const f32x4*)&As[r * 256 + (((g0    ) ^ (r & 7)) << 2)];
            f32x4 f1 = *(const f32x4*)&As[r * 256 + (((g0 + 1) ^ (r & 7)) << 2)];
            xfr[i] = pack8v(f0, f1);
        }
#pragma unroll
        for (int j = 0; j < 2; ++j)
#pragma unroll
            for (int i = 0; i < 2; ++i)
                acc[i][j] = __builtin_amdgcn_mfma_f32_16x16x32_bf16(
                    wfr[j][kk], xfr[i], acc[i][j], 0, 0, 0);
    }

    // ---- Epilogue. A=W, B=x -> col(lane&15)=tile row, row(quad*4+reg)=d.
#pragma unroll
    for (int j = 0; j < 2; ++j) {
        const int d0 = w8 * 32 + j * 16 + quad * 4;
#pragma unroll
        for (int i = 0; i < 2; ++i) {
            const int rg = i * 16 + lrow;
            if (rg <= rmax) {
                f32x4 v = acc[i][j] + bj[j];
                *(f32x4*)(out + (xrow0 + rstride * rg) * H_ + d0) = v;
            }
        }
    }
}

extern "C" void kernel_launch(void* const* d_in, const int* in_sizes, int n_in,
                              void* d_out, int out_size, void* d_ws, size_t ws_size,
                              hipStream_t stream) {
    const float* x    = (const float*)d_in[0];
    const float* W    = (const float*)d_in[1];
    const float* bias = (const float*)d_in[2];
    float* out = (float*)d_out;

    const size_t w_elems  = (size_t)5 * H_ * H_;
    const size_t ws_need  = w_elems * sizeof(unsigned short) + H_ * sizeof(float);

    const int grid = 2048 + 12;
    if (ws_size >= ws_need) {
        unsigned short* Wbf = (unsigned short*)d_ws;
        float* bsum = (float*)((char*)d_ws + w_elems * sizeof(unsigned short));
        prep_kernel<<<dim3(160), dim3(256), 0, stream>>>(W, bias, Wbf, bsum);
        sel_gemm_kernel<0><<<dim3(grid), dim3(512), 0, stream>>>(
            x, (const void*)Wbf, (const void*)bsum, out);
    } else {
        sel_gemm_kernel<1><<<dim3(grid), dim3(512), 0, stream>>>(
            x, (const void*)W, (const void*)bias, out);
    }
}